// Round 6
// baseline (207.900 us; speedup 1.0000x reference)
//
#include <hip/hip_runtime.h>
#include <math.h>

#define SEQ 2048
#define NH 8
#define HD 128
#define DIMF 1024
#define LOG2E 1.4426950408889634f

typedef __attribute__((ext_vector_type(8))) short bf16x8;
typedef __attribute__((ext_vector_type(8))) unsigned short us8;
typedef __attribute__((ext_vector_type(4))) float f32x4;

// persistent scratch (fully rewritten every launch; no stale-state dependence)
__device__ float g_itacc[NH*SEQ];
__device__ float g_ftacc[NH*SEQ];
__device__ float g_aL[NH*SEQ];     // (itilde - csum)*log2e - 3.5  (log2(1/TAU) folded in)
__device__ float g_cmL[NH*SEQ];    // cummax(a) * log2e
__device__ float g_en[NH*SEQ];     // exp(-(csum + cummax)) = exp(-max_d)
__device__ unsigned short g_Qb[NH*SEQ*HD];  // bf16, [h][s][d]
__device__ unsigned short g_Kb[NH*SEQ*HD];
__device__ unsigned short g_Vb[NH*SEQ*HD];
__device__ unsigned short g_Vt[NH*HD*SEQ];  // bf16, [h][d][s]  (V transposed)
__device__ unsigned short g_Wb[16*3072];    // bf16, rows 0..7 = Wi, 8..15 = Wf
// j-chunk partials: 640 slots (8 heads x 80 chunk-slots)
__device__ float g_Opart[640*64*128];       // fp32 partial O tiles
__device__ float g_Spart[640*64];           // fp32 partial rowsums

__device__ __forceinline__ unsigned short f2bf(float x) {
  unsigned u = __float_as_uint(x);
  u += 0x7fffu + ((u >> 16) & 1u);   // RNE
  return (unsigned short)(u >> 16);
}

// ------- kernel 1: all input prep in one launch -------
// bid 0..4095    : q/k fp32 -> bf16 [h][s][d]
// bid 4096..4143 : Wi/Wf -> bf16
// bid 4144..4655 : v fp32 -> bf16 g_Vb[h][s][d] AND transposed g_Vt[h][d][s]
__global__ __launch_bounds__(256) void prep_kernel(const float* __restrict__ q,
                                                   const float* __restrict__ k,
                                                   const float* __restrict__ v,
                                                   const float* __restrict__ Wi,
                                                   const float* __restrict__ Wf) {
  __shared__ __align__(16) unsigned short Ts[64*72];
  const int bid = blockIdx.x;
  if (bid < 4096) {
    const int s = bid & 2047;
    const int t = bid >> 11;
    const float* src = (t == 0) ? q : k;
    unsigned short* dst = (t == 0) ? g_Qb : g_Kb;
    const int c = threadIdx.x * 4;
    const float4 f = *(const float4*)(src + s*DIMF + c);
    const int h = c >> 7, d = c & 127;
    ushort4 u;
    u.x = f2bf(f.x); u.y = f2bf(f.y); u.z = f2bf(f.z); u.w = f2bf(f.w);
    *(ushort4*)(dst + (h*SEQ + s)*HD + d) = u;
  } else if (bid < 4144) {
    const int gid = (bid - 4096) * 256 + threadIdx.x;
    const int e4 = gid * 4;           // 48 blocks * 1024 = 49152 = 16*3072 exactly
    const int p = e4 / 3072;
    const int c = e4 % 3072;
    const float* src = (p < 8) ? (Wi + p*3072 + c) : (Wf + (p-8)*3072 + c);
    const float4 f = *(const float4*)src;
    ushort4 u;
    u.x = f2bf(f.x); u.y = f2bf(f.y); u.z = f2bf(f.z); u.w = f2bf(f.w);
    *(ushort4*)(g_Wb + p*3072 + c) = u;
  } else {
    const int b2 = bid - 4144;        // 512 = 8h x 32s0 x 2d0
    const int h  = b2 & 7;
    const int s0 = ((b2 >> 3) & 31) * 64;
    const int d0 = (b2 >> 8) * 64;
    const int t = threadIdx.x;
    { // load 64 s-rows x 64 d-cols fp32, convert, stash to LDS + g_Vb
      const int sr = t >> 2;
      const int c  = (t & 3) * 16;
      const float* src = v + (s0 + sr)*DIMF + h*HD + d0 + c;
      unsigned short tmp[16];
      #pragma unroll
      for (int i = 0; i < 4; ++i) {
        const float4 f = *(const float4*)&src[i*4];
        tmp[i*4+0] = f2bf(f.x); tmp[i*4+1] = f2bf(f.y);
        tmp[i*4+2] = f2bf(f.z); tmp[i*4+3] = f2bf(f.w);
      }
      *(us8*)&Ts[sr*72 + c]     = *(us8*)&tmp[0];
      *(us8*)&Ts[sr*72 + c + 8] = *(us8*)&tmp[8];
      unsigned short* vb = g_Vb + (h*SEQ + s0 + sr)*HD + d0 + c;
      *(us8*)&vb[0] = *(us8*)&tmp[0];
      *(us8*)&vb[8] = *(us8*)&tmp[8];
    }
    __syncthreads();
    { // transposed store: wave w covers s-cols [w*16,w*16+16), lane l = d-row
      const int w = t >> 6, l = t & 63;
      unsigned short outv[16];
      #pragma unroll
      for (int j = 0; j < 16; ++j) outv[j] = Ts[(w*16 + j)*72 + l];
      unsigned short* dst = g_Vt + (h*HD + d0 + l)*SEQ + s0 + w*16;
      *(us8*)&dst[0] = *(us8*)&outv[0];
      *(us8*)&dst[8] = *(us8*)&outv[8];
    }
  }
}

// ------- kernel 2: gate projections via MFMA (M=2048, N=16, K=3072) -------
__global__ __launch_bounds__(256) void gates_kernel() {
  __shared__ f32x4 red[4][64];
  const int tid = threadIdx.x;
  const int wave = tid >> 6, lane = tid & 63;
  const int q4 = lane >> 4, l16 = lane & 15;
  const int s0 = blockIdx.x * 16;
  f32x4 acc = {0.f, 0.f, 0.f, 0.f};
  #pragma unroll 8
  for (int ks = wave*24; ks < wave*24 + 24; ++ks) {
    const int k0 = ks*32 + q4*8;          // global k of this lane's 8 elems
    const int tsel = k0 >> 10;
    const int rem = k0 & 1023;
    const int hh = rem >> 7, dd = rem & 127;
    const unsigned short* base = (tsel == 0) ? g_Qb : (tsel == 1) ? g_Kb : g_Vb;
    const bf16x8 a = *(const bf16x8*)&base[(hh*SEQ + s0 + l16)*HD + dd];
    const bf16x8 b = *(const bf16x8*)&g_Wb[l16*3072 + k0];
    acc = __builtin_amdgcn_mfma_f32_16x16x32_bf16(a, b, acc, 0, 0, 0);
  }
  red[wave][lane] = acc;
  __syncthreads();
  if (wave == 0) {
    f32x4 s = red[0][lane];
    #pragma unroll
    for (int w = 1; w < 4; ++w) s += red[w][lane];
    #pragma unroll
    for (int r = 0; r < 4; ++r) {
      const int sg = s0 + 4*q4 + r;       // C/D: row = quad*4+reg, col = l16
      if (l16 < 8) g_itacc[l16*SEQ + sg] = s[r];
      else         g_ftacc[(l16-8)*SEQ + sg] = s[r];
    }
  }
}

// ------- kernel 3: per-head scans (block scan, 256 threads, 8 elems/thread) -------
__global__ __launch_bounds__(256) void scan_kernel(const float* __restrict__ Wi_b,
                                                   const float* __restrict__ Wf_b) {
  __shared__ float Wsum[4];
  __shared__ float Wmax[4];
  const int h = blockIdx.x;
  const int t = threadIdx.x;
  const int wave = t >> 6, lane = t & 63;
  const float ib = Wi_b[h];
  const float fb = Wf_b[h];
  const int base = h*SEQ + t*8;

  float it[8], ft[8];
  *(float4*)&it[0] = *(const float4*)&g_itacc[base];
  *(float4*)&it[4] = *(const float4*)&g_itacc[base+4];
  *(float4*)&ft[0] = *(const float4*)&g_ftacc[base];
  *(float4*)&ft[4] = *(const float4*)&g_ftacc[base+4];

  float cs[8];
  float run = 0.f;
  #pragma unroll
  for (int j = 0; j < 8; ++j) {
    const float f = ft[j] + fb;
    const float ls = fminf(f, 0.f) - log1pf(expf(-fabsf(f)));  // logsigmoid
    run += ls;
    cs[j] = run;
  }
  float x = run;
  #pragma unroll
  for (int off = 1; off < 64; off <<= 1) {
    const float tv = __shfl_up(x, off, 64);
    if (lane >= off) x += tv;
  }
  const float wexcl = x - run;
  if (lane == 63) Wsum[wave] = x;
  __syncthreads();
  float boff = 0.f;
  #pragma unroll
  for (int w = 0; w < 4; ++w) if (w < wave) boff += Wsum[w];
  const float cbase = boff + wexcl;

  float a[8], am[8], csum[8];
  float m = -__builtin_inff();
  #pragma unroll
  for (int j = 0; j < 8; ++j) {
    csum[j] = cbase + cs[j];
    a[j] = (it[j] + ib) - csum[j];
    m = fmaxf(m, a[j]);
    am[j] = m;
  }
  float y = m;
  #pragma unroll
  for (int off = 1; off < 64; off <<= 1) {
    const float tv = __shfl_up(y, off, 64);
    if (lane >= off) y = fmaxf(y, tv);
  }
  float e = __shfl_up(y, 1, 64);
  if (lane == 0) e = -__builtin_inff();
  if (lane == 63) Wmax[wave] = y;
  __syncthreads();
  float bmax = -__builtin_inff();
  #pragma unroll
  for (int w = 0; w < 4; ++w) if (w < wave) bmax = fmaxf(bmax, Wmax[w]);
  const float pre = fmaxf(bmax, e);

  float oa[8], ocm[8], oen[8];
  #pragma unroll
  for (int j = 0; j < 8; ++j) {
    const float cm = fmaxf(pre, am[j]);
    oa[j]  = a[j] * LOG2E - 3.5f;        // log2(1/TAU) = -3.5 folded in
    ocm[j] = cm * LOG2E;
    oen[j] = expf(-(csum[j] + cm));
  }
  *(float4*)&g_aL[base]    = *(float4*)&oa[0];
  *(float4*)&g_aL[base+4]  = *(float4*)&oa[4];
  *(float4*)&g_cmL[base]   = *(float4*)&ocm[0];
  *(float4*)&g_cmL[base+4] = *(float4*)&ocm[4];
  *(float4*)&g_en[base]    = *(float4*)&oen[0];
  *(float4*)&g_en[base+4]  = *(float4*)&oen[4];
}

// ------- kernel 4: decay attention, wave-independent 16-row strips, NO barriers -------
// grid = (8 heads, 80 chunk-slots); linear%8 pins head->XCD (K/V L2-resident).
// Each of the 4 waves owns rows [i0+16w, i0+16w+16) and runs the whole j-chunk
// privately: K frags global->reg at loop top; V frags issued right after QK so
// the P-computation (exp2/pack) covers their latency; P round-trips a per-wave
// LDS buffer (intra-wave lgkmcnt ordering only). Zero __syncthreads.
__global__ __launch_bounds__(256, 3) void attn1_kernel() {
  __shared__ __align__(16) unsigned short Pl[4][16*72];   // per-wave P buffer

  const int h = blockIdx.x;
  const int y = blockIdx.y;
  int g, s0g;
  if      (y < 8)  { g = 0; s0g = 0;  }
  else if (y < 24) { g = 1; s0g = 8;  }
  else if (y < 48) { g = 2; s0g = 24; }
  else             { g = 3; s0g = 48; }
  const int rel = y - s0g;
  const int iT  = 8*g + rel/(g+1);
  const int ch  = rel - (rel/(g+1))*(g+1);
  const int slot = h*80 + y;
  const int i0 = iT*64;
  const int jt0 = ch*8;
  const int jt1 = (jt0 + 8 < iT + 1) ? (jt0 + 8) : (iT + 1);

  const int tid = threadIdx.x;
  const int wave = tid >> 6;
  const int lane = tid & 63;
  const int q4 = lane >> 4;
  const int l16 = lane & 15;
  const int ir0 = i0 + 16*wave;        // this wave's 16 rows
  unsigned short* Pw = &Pl[wave][0];

  // Q A-fragments (A: m = l16, k = q4*8 + j)
  bf16x8 qa[4];
  {
    const unsigned short* Qg = g_Qb + (h*SEQ + ir0 + l16)*HD;
    #pragma unroll
    for (int ks = 0; ks < 4; ++ks) qa[ks] = *(const bf16x8*)&Qg[ks*32 + q4*8];
  }

  float cmv[4];
  #pragma unroll
  for (int r = 0; r < 4; ++r) cmv[r] = g_cmL[h*SEQ + ir0 + 4*q4 + r];

  f32x4 acc[8];
  float rs[4];
  const f32x4 fzero = {0.f, 0.f, 0.f, 0.f};
  #pragma unroll
  for (int tc = 0; tc < 8; ++tc) acc[tc] = fzero;
  #pragma unroll
  for (int r = 0; r < 4; ++r) rs[r] = 0.f;

  const unsigned short* Kgh = g_Kb + h*SEQ*HD;
  const unsigned short* Vgh = g_Vt + h*HD*SEQ;
  const float* aLg = g_aL + h*SEQ;

  for (int jt = jt0; jt < jt1; ++jt) {
    const int j0 = jt*64;

    float aLv[4];
    #pragma unroll
    for (int jc = 0; jc < 4; ++jc) aLv[jc] = aLg[j0 + jc*16 + l16];

    // K B-frags: full 64x128 tile across the wave (B: n = l16-row of K, k = q4*8+j)
    bf16x8 kf[16];
    #pragma unroll
    for (int jc = 0; jc < 4; ++jc)
      #pragma unroll
      for (int ks = 0; ks < 4; ++ks)
        kf[jc*4+ks] = *(const bf16x8*)&Kgh[(j0 + jc*16 + l16)*HD + ks*32 + q4*8];

    // QK^T: 16 MFMA (kf dies here -> regs reused for vf)
    f32x4 c[4] = {fzero, fzero, fzero, fzero};
    #pragma unroll
    for (int ks = 0; ks < 4; ++ks)
      #pragma unroll
      for (int jc = 0; jc < 4; ++jc)
        c[jc] = __builtin_amdgcn_mfma_f32_16x16x32_bf16(qa[ks], kf[jc*4+ks], c[jc], 0, 0, 0);

    // V^T B-frags issued NOW; P computation below covers their L2 latency
    bf16x8 vf[16];
    #pragma unroll
    for (int tc = 0; tc < 8; ++tc)
      #pragma unroll
      for (int ks = 0; ks < 2; ++ks)
        vf[tc*2+ks] = *(const bf16x8*)&Vgh[(tc*16 + l16)*SEQ + j0 + ks*32 + q4*8];

    // P = dot * exp2(aL_j - cmL_i)  (1/TAU folded into aL); causal mask on diag
    const bool diag = (jt == iT);
    #pragma unroll
    for (int jc = 0; jc < 4; ++jc) {
      const int jg = j0 + jc*16 + l16;
      #pragma unroll
      for (int r = 0; r < 4; ++r) {
        const int ig = ir0 + 4*q4 + r;
        float p = c[jc][r] * exp2f(aLv[jc] - cmv[r]);
        if (diag && (jg > ig)) p = 0.f;
        rs[r] += p;
        Pw[(4*q4 + r)*72 + jc*16 + l16] = f2bf(p);
      }
    }

    // P A-frags (compiler inserts lgkmcnt; intra-wave ordering, no barrier)
    const bf16x8 pf0 = *(const bf16x8*)&Pw[l16*72 + q4*8];
    const bf16x8 pf1 = *(const bf16x8*)&Pw[l16*72 + 32 + q4*8];

    // PV: 16 MFMA
    #pragma unroll
    for (int tc = 0; tc < 8; ++tc) {
      acc[tc] = __builtin_amdgcn_mfma_f32_16x16x32_bf16(pf0, vf[tc*2+0], acc[tc], 0, 0, 0);
      acc[tc] = __builtin_amdgcn_mfma_f32_16x16x32_bf16(pf1, vf[tc*2+1], acc[tc], 0, 0, 0);
    }
  }

  // rowsum across the 16 column-lanes (wave-local; rows owned exclusively)
  #pragma unroll
  for (int r = 0; r < 4; ++r) {
    float t = rs[r];
    t += __shfl_xor(t, 1, 16);
    t += __shfl_xor(t, 2, 16);
    t += __shfl_xor(t, 4, 16);
    t += __shfl_xor(t, 8, 16);
    rs[r] = t;
  }
  if (l16 == 0) {
    #pragma unroll
    for (int r = 0; r < 4; ++r)
      g_Spart[slot*64 + 16*wave + 4*q4 + r] = rs[r];
  }

  float* Ob = g_Opart + slot*(64*128);
  #pragma unroll
  for (int tc = 0; tc < 8; ++tc)
    #pragma unroll
    for (int r = 0; r < 4; ++r)
      Ob[(16*wave + 4*q4 + r)*128 + tc*16 + l16] = acc[tc][r];
}

// ------- kernel 5: reduce partials + maxit normalize + GroupNorm -------
__global__ __launch_bounds__(256) void reduce_kernel(const float* __restrict__ gnw,
                                                     const float* __restrict__ gnb,
                                                     float* __restrict__ out) {
  const int h  = blockIdx.x;
  const int iT = blockIdx.y;
  const int t  = threadIdx.x;
  const int r  = t >> 2;
  const int qd = t & 3;
  const int qq = iT >> 3;
  const int nch = qq + 1;
  const int slot0 = h*80 + iT + 4*qq*(qq-1) + qq*(iT & 7);

  float acc[32];
  #pragma unroll
  for (int e = 0; e < 32; ++e) acc[e] = 0.f;
  float S = 0.f;
  for (int c = 0; c < nch; ++c) {
    const float* Ob = g_Opart + (slot0 + c)*(64*128) + r*128 + qd*32;
    #pragma unroll
    for (int kk = 0; kk < 8; ++kk) {
      const float4 f = *(const float4*)&Ob[kk*4];
      acc[kk*4+0] += f.x; acc[kk*4+1] += f.y; acc[kk*4+2] += f.z; acc[kk*4+3] += f.w;
    }
    S += g_Spart[(slot0 + c)*64 + r];
  }

  const float en = g_en[h*SEQ + iT*64 + r];
  const float sc = 1.f / (fmaxf(fabsf(S), en) + 1e-6f);
  float s1 = 0.f, s2 = 0.f;
  #pragma unroll
  for (int e = 0; e < 32; ++e) {
    const float xv = acc[e] * sc;
    acc[e] = xv;
    s1 += xv;
    s2 += xv * xv;
  }
  s1 += __shfl_xor(s1, 1, 4); s2 += __shfl_xor(s2, 1, 4);
  s1 += __shfl_xor(s1, 2, 4); s2 += __shfl_xor(s2, 2, 4);
  const float mean = s1 * (1.f/128.f);
  const float var  = s2 * (1.f/128.f) - mean*mean;
  const float rstd = rsqrtf(var + 1e-5f);

  const float* gw = gnw + h*HD + qd*32;
  const float* gb = gnb + h*HD + qd*32;
  float* op = out + (iT*64 + r)*DIMF + h*HD + qd*32;
  #pragma unroll
  for (int kk = 0; kk < 8; ++kk) {
    const float4 w4 = *(const float4*)&gw[kk*4];
    const float4 b4 = *(const float4*)&gb[kk*4];
    float4 o;
    o.x = (acc[kk*4+0] - mean) * rstd * w4.x + b4.x;
    o.y = (acc[kk*4+1] - mean) * rstd * w4.y + b4.y;
    o.z = (acc[kk*4+2] - mean) * rstd * w4.z + b4.z;
    o.w = (acc[kk*4+3] - mean) * rstd * w4.w + b4.w;
    *(float4*)&op[kk*4] = o;
  }
}

extern "C" void kernel_launch(void* const* d_in, const int* in_sizes, int n_in,
                              void* d_out, int out_size, void* d_ws, size_t ws_size,
                              hipStream_t stream) {
  (void)in_sizes; (void)n_in; (void)out_size; (void)d_ws; (void)ws_size;
  const float* q    = (const float*)d_in[0];
  const float* k    = (const float*)d_in[1];
  const float* v    = (const float*)d_in[2];
  const float* Wi_w = (const float*)d_in[3];
  const float* Wi_b = (const float*)d_in[4];
  const float* Wf_w = (const float*)d_in[5];
  const float* Wf_b = (const float*)d_in[6];
  const float* gnw  = (const float*)d_in[7];
  const float* gnb  = (const float*)d_in[8];
  float* out = (float*)d_out;

  prep_kernel<<<dim3(4656), 256, 0, stream>>>(q, k, v, Wi_w, Wf_w);
  gates_kernel<<<dim3(128), 256, 0, stream>>>();
  scan_kernel<<<dim3(NH), 256, 0, stream>>>(Wi_b, Wf_b);
  attn1_kernel<<<dim3(NH, 80), 256, 0, stream>>>();
  reduce_kernel<<<dim3(NH, SEQ/64), 256, 0, stream>>>(gnw, gnb, out);
}